// Round 12
// baseline (23.799 us; speedup 1.0000x reference)
//
#include <hip/hip_runtime.h>

// Algebraic collapse (verified exactly, absmax 0.0 across rounds):
//   softmax over the QUERY axis => sum_q attn[b,q,k] == 1 for all (b,k), so
//   context.mean(axis=0) = mean_k V[k,b,:] = xbar @ Wv.T + bv, and
//   out[b,h] = xbar[b,h] + sum_j xbar[b,j]*Wv[h,j] + bv[h],  xbar = x.mean(0).
//   Wq, bq, Wk, bk drop out of the output entirely.
// Lessons:
//   R2: NO cooperative grid.sync on MI355X (~100us/sync).
//   R3-R10 colsum shape scan: good regime = {SCHUNK=32, part<=2MiB}.
//     SCHUNK<=16 or part>=4MiB: +12us flat (incl. fully-contiguous R9).
//     Width at 256blk: 8KB=26.9 > 4KB=23.9. R11: +nt loads -> 23.6 (keep).
//   R7: k_out wave-per-(h,8b) Wv-register-reuse. FROZEN.
//   Dispatch fusion structurally closed: last-block fold needs per-call
//     zeroed counter (ws not re-poisoned between replays; extra memset
//     dispatch cancels the gain); fold-in-k_out duplicates ~1GiB L2 reads.
//   R12 probe: the un-isolated corner {1024 blocks, SCHUNK=32} => 2KB runs,
//     16 waves/CU (4/SIMD, 2x occupancy). nt kept. reduce/out byte-identical.

constexpr int S = 1024;
constexpr int B = 16;
constexpr int H = 1024;
constexpr int C = B * H;            // 16384 columns when x is viewed [S][B*H]
constexpr int C4 = C / 4;           // 4096 float4 columns
constexpr int SPLITS = 32;          // S-axis split (frozen good value)
constexpr int SCHUNK = S / SPLITS;  // 32 rows per block
constexpr int CHUNKS = 32;          // column chunks -> 2KB-wide strips
constexpr int CW = C4 / CHUNKS;     // 128 float4 per strip

typedef float f4v __attribute__((ext_vector_type(4)));

// --- K1: partial column sums. grid (32, 32) = 1024 blocks, block 256.
// Block: 2KB-wide strip x 32 rows; two threads share a strip-row pair:
// thread t covers column c4 = cx*128 + (t&127), rows split by... no:
// 256 threads, 128 float4 columns -> thread t: column (t&127), row-half
// (t>>7). Each thread sums 16 rows; the two half-sums are combined in
// LDS-free fashion via a final add by the low half. To preserve the exact
// per-column ascending add order (absmax 0.0), we instead keep one thread
// per column with 2 columns' worth... simpler: 128 threads would waste.
// => Keep one-thread-per-column ORDER by letting thread t (t<128) own
// column t and sum rows 0..31 ascending; threads 128..255 own column
// (t-128)+... there are only 128 columns per strip. So: each block covers
// TWO adjacent strips: c4 = cx*256 + t, rows 0..31. grid (16,64)? That's
// SPLITS=64 (part 4MiB, bad regime). Resolution: block covers one strip of
// 256 float4 = 4KB (as R11) but grid.x=16 ... that IS R11.
// => True 2KB probe needs 128-thr blocks: grid (32,32), block 128.
__global__ void __launch_bounds__(128) k_colsum(const f4v* __restrict__ x4,
                                                f4v* __restrict__ part4) {
    const int c4 = blockIdx.x * 128 + threadIdx.x;   // [0, 4096)
    const int split = blockIdx.y;
    const f4v* p = x4 + (size_t)split * SCHUNK * C4 + c4;
    f4v a = (f4v){0.f, 0.f, 0.f, 0.f};
#pragma unroll
    for (int i = 0; i < SCHUNK; ++i) {
        f4v v = __builtin_nontemporal_load(p + (size_t)i * C4);
        a += v;   // same per-column ascending add order as R11
    }
    part4[(size_t)split * C4 + c4] = a;
}

// --- K1.5 (byte-identical): fold 32 partial rows -> xsum[C].
__global__ void k_reduce(const float* __restrict__ part, float* __restrict__ xsum) {
    const int c = blockIdx.x * blockDim.x + threadIdx.x;
    float a = 0.f;
#pragma unroll
    for (int t = 0; t < SPLITS; ++t) a += part[(size_t)t * C + c];
    xsum[c] = a;
}

// --- K2 (R7-frozen): one wave per (h, b-octet). 512 blocks x 256 = 2048 waves.
__global__ void __launch_bounds__(256) k_out(const float* __restrict__ xsum,
                                             const float* __restrict__ Wv,
                                             const float* __restrict__ bv,
                                             float* __restrict__ out) {
    const int wid  = (blockIdx.x * 256 + threadIdx.x) >> 6;  // [0, 2048)
    const int lane = threadIdx.x & 63;
    const int h    = wid >> 1;           // [0, 1024)
    const int bh   = (wid & 1) * 8;      // 0 or 8

    const float4* wr = (const float4*)(Wv + (size_t)h * H);  // 256 float4/row
    const float4 w0 = wr[lane], w1 = wr[lane + 64],
                 w2 = wr[lane + 128], w3 = wr[lane + 192];
    const float bvh = bv[h];

    float acc[8];
#pragma unroll
    for (int b = 0; b < 8; ++b) {
        const float4* xr = (const float4*)(xsum + (size_t)(bh + b) * H);
        const float4 a0 = xr[lane], a1 = xr[lane + 64],
                     a2 = xr[lane + 128], a3 = xr[lane + 192];
        acc[b] = a0.x * w0.x + a0.y * w0.y + a0.z * w0.z + a0.w * w0.w
               + a1.x * w1.x + a1.y * w1.y + a1.z * w1.z + a1.w * w1.w
               + a2.x * w2.x + a2.y * w2.y + a2.z * w2.z + a2.w * w2.w
               + a3.x * w3.x + a3.y * w3.y + a3.z * w3.z + a3.w * w3.w;
    }
#pragma unroll
    for (int b = 0; b < 8; ++b) {
#pragma unroll
        for (int off = 32; off; off >>= 1) acc[b] += __shfl_down(acc[b], off, 64);
    }
    if (lane == 0) {
#pragma unroll
        for (int b = 0; b < 8; ++b) {
            const int c = (bh + b) * H + h;
            out[c] = (xsum[c] + acc[b]) * (1.0f / (float)S) + bvh;
        }
    }
}

extern "C" void kernel_launch(void* const* d_in, const int* in_sizes, int n_in,
                              void* d_out, int out_size, void* d_ws, size_t ws_size,
                              hipStream_t stream) {
    const float* x  = (const float*)d_in[0];
    // d_in[1..4] (Wq,bq,Wk,bk) are provably unused (see header).
    const float* Wv = (const float*)d_in[5];
    const float* bv = (const float*)d_in[6];
    float* out = (float*)d_out;
    float* ws  = (float*)d_ws;

    float* part = ws;                       // [SPLITS][C]  = 2 MiB
    float* xsum = ws + (size_t)SPLITS * C;  // [C]
    k_colsum<<<dim3(CHUNKS, SPLITS), 128, 0, stream>>>(
        (const f4v*)x, (f4v*)part);
    k_reduce<<<C / 256, 256, 0, stream>>>(part, xsum);
    k_out<<<512, 256, 0, stream>>>(xsum, Wv, bv, out);
}